// Round 4
// baseline (2532.831 us; speedup 1.0000x reference)
//
#include <hip/hip_runtime.h>
#include <hip/hip_bf16.h>
#include <math.h>

#define B_  2
#define N_  384
#define D_  256
#define PD_ 64
#define L_  8
#define H_  8
#define DH_ 32

// ---------------- embed + pos-enc + LN ----------------
__global__ void embed_ln_kernel(const int* __restrict__ tokens, const float* __restrict__ tok_emb,
                                const float* __restrict__ lnw, const float* __restrict__ lnb,
                                float* __restrict__ x) {
  int row = blockIdx.x;            // b*N + n
  int n = row % N_;
  int d = threadIdx.x;             // 0..255
  int tok = tokens[row];
  float val = tok_emb[tok * D_ + d];
  int i = d >> 1;
  float dv = expf((float)(2 * i) * (-logf(10000.0f) / (float)D_));
  float ang = (float)n * dv;
  val += (d & 1) ? cosf(ang) : sinf(ang);

  __shared__ float rbuf[256];
  rbuf[d] = val; __syncthreads();
  for (int s = 128; s > 0; s >>= 1) { if (d < s) rbuf[d] += rbuf[d + s]; __syncthreads(); }
  float mean = rbuf[0] / D_;
  __syncthreads();
  rbuf[d] = val * val; __syncthreads();
  for (int s = 128; s > 0; s >>= 1) { if (d < s) rbuf[d] += rbuf[d + s]; __syncthreads(); }
  float var = rbuf[0] / D_ - mean * mean;
  float r = rsqrtf(var + 1e-5f);
  x[row * D_ + d] = (val - mean) * r * lnw[d] + lnb[d];
}

// ---------------- generic per-row GEMM: C = act(A@W + bias) ----------------
// act: 0 none, 1 relu
__global__ void gemm_rows_kernel(const float* __restrict__ A, const float* __restrict__ W,
                                 const float* __restrict__ bias,
                                 float* __restrict__ C, int K, int Nc, int act) {
  int row = blockIdx.x;
  int tid = threadIdx.x;
  __shared__ float sA[256];
  for (int kk = tid; kk < K; kk += 256) sA[kk] = A[row * K + kk];
  __syncthreads();
  for (int c = tid; c < Nc; c += 256) {
    float acc = bias ? bias[c] : 0.0f;
    const float* wp = W + c;
    for (int kk = 0; kk < K; kk++) acc = fmaf(sA[kk], wp[(size_t)kk * Nc], acc);
    if (act == 1) acc = fmaxf(acc, 0.0f);
    C[row * Nc + c] = acc;
  }
}

// ---------------- SE3 frame attention: one block per (b,i,h) ----------------
__global__ void attn_kernel(const float* __restrict__ Q, const float* __restrict__ K,
                            const float* __restrict__ V, const float* __restrict__ frames,
                            float* __restrict__ AO) {
  int idx = blockIdx.x;
  int h = idx % H_;
  int bi = idx / H_;               // b*N + i
  int b = bi / N_;
  int tid = threadIdx.x;           // 256
  __shared__ float sq[DH_];
  __shared__ float sc[N_];
  __shared__ float rbuf[256];
  if (tid < DH_) sq[tid] = Q[bi * D_ + h * DH_ + tid];
  float ti0 = frames[bi * 16 + 3], ti1 = frames[bi * 16 + 7], ti2 = frames[bi * 16 + 11];
  __syncthreads();
  for (int j = tid; j < N_; j += 256) {
    int bj = b * N_ + j;
    const float* kp = K + bj * D_ + h * DH_;
    float dot = 0.0f;
    #pragma unroll
    for (int dd = 0; dd < DH_; dd++) dot = fmaf(sq[dd], kp[dd], dot);
    float dx = ti0 - frames[bj * 16 + 3];
    float dy = ti1 - frames[bj * 16 + 7];
    float dz = ti2 - frames[bj * 16 + 11];
    sc[j] = dot * 0.17677669529663689f - (dx * dx + dy * dy + dz * dz);
  }
  __syncthreads();
  float m = -1e30f;
  for (int j = tid; j < N_; j += 256) m = fmaxf(m, sc[j]);
  rbuf[tid] = m; __syncthreads();
  for (int s = 128; s > 0; s >>= 1) { if (tid < s) rbuf[tid] = fmaxf(rbuf[tid], rbuf[tid + s]); __syncthreads(); }
  m = rbuf[0]; __syncthreads();
  float ps = 0.0f;
  for (int j = tid; j < N_; j += 256) { float e = expf(sc[j] - m); sc[j] = e; ps += e; }
  rbuf[tid] = ps; __syncthreads();
  for (int s = 128; s > 0; s >>= 1) { if (tid < s) rbuf[tid] += rbuf[tid + s]; __syncthreads(); }
  float inv = 1.0f / rbuf[0];
  __syncthreads();
  int dd = tid & (DH_ - 1);
  int g  = tid >> 5;               // 0..7
  float acc = 0.0f;
  for (int j = g; j < N_; j += 8)
    acc = fmaf(sc[j], V[(size_t)(b * N_ + j) * D_ + h * DH_ + dd], acc);
  rbuf[tid] = acc; __syncthreads();
  if (tid < DH_) {
    float s = 0.0f;
    #pragma unroll
    for (int gg = 0; gg < 8; gg++) s += rbuf[gg * 32 + tid];
    AO[bi * D_ + h * DH_ + tid] = s * inv;
  }
}

// ---------------- x = LN(x + add) ----------------
__global__ void add_ln_kernel(const float* __restrict__ X, const float* __restrict__ Add,
                              const float* __restrict__ lnw, const float* __restrict__ lnb,
                              float* __restrict__ Out) {
  int row = blockIdx.x;
  int d = threadIdx.x;
  float val = X[row * D_ + d] + Add[row * D_ + d];
  __shared__ float rbuf[256];
  rbuf[d] = val; __syncthreads();
  for (int s = 128; s > 0; s >>= 1) { if (d < s) rbuf[d] += rbuf[d + s]; __syncthreads(); }
  float mean = rbuf[0] / D_;
  __syncthreads();
  rbuf[d] = val * val; __syncthreads();
  for (int s = 128; s > 0; s >>= 1) { if (d < s) rbuf[d] += rbuf[d + s]; __syncthreads(); }
  float var = rbuf[0] / D_ - mean * mean;
  float r = rsqrtf(var + 1e-5f);
  Out[row * D_ + d] = (val - mean) * r * lnw[d] + lnb[d];
}

// ---------------- fused FF: x += gelu(LN(x)@W1+b1)@W2+b2 (in place) ----------------
__global__ void fused_ff_kernel(float* __restrict__ x,
                                const float* __restrict__ lnw, const float* __restrict__ lnb,
                                const float* __restrict__ W1, const float* __restrict__ b1,
                                const float* __restrict__ W2, const float* __restrict__ b2) {
  int row = blockIdx.x;
  int tid = threadIdx.x;           // 256
  __shared__ float sh[256];        // LN'd h
  __shared__ float sf[1024];       // gelu(h@W1+b1)
  __shared__ float rbuf[256];
  float xv = x[row * D_ + tid];
  rbuf[tid] = xv; __syncthreads();
  for (int s = 128; s > 0; s >>= 1) { if (tid < s) rbuf[tid] += rbuf[tid + s]; __syncthreads(); }
  float mean = rbuf[0] / D_;
  __syncthreads();
  rbuf[tid] = xv * xv; __syncthreads();
  for (int s = 128; s > 0; s >>= 1) { if (tid < s) rbuf[tid] += rbuf[tid + s]; __syncthreads(); }
  float var = rbuf[0] / D_ - mean * mean;
  float r = rsqrtf(var + 1e-5f);
  sh[tid] = (xv - mean) * r * lnw[tid] + lnb[tid];
  __syncthreads();
  for (int c = tid; c < 1024; c += 256) {
    float acc = b1[c];
    const float* wp = W1 + c;
    for (int kk = 0; kk < 256; kk++) acc = fmaf(sh[kk], wp[(size_t)kk * 1024], acc);
    sf[c] = 0.5f * acc * (1.0f + erff(acc * 0.7071067811865475f));  // exact gelu
  }
  __syncthreads();
  float acc2 = b2[tid];
  const float* wp2 = W2 + tid;
  for (int kk = 0; kk < 1024; kk++) acc2 = fmaf(sf[kk], wp2[(size_t)kk * 256], acc2);
  x[row * D_ + tid] = xv + acc2;
}

// ---------------- pair LN + mean over j ----------------
__global__ void pair_mean_kernel(const float* __restrict__ proj, const float* __restrict__ relpos,
                                 const float* __restrict__ lnw, const float* __restrict__ lnb,
                                 float* __restrict__ pairm) {
  int row = blockIdx.x;            // b*N + i
  int b = row / N_;
  int i = row % N_;
  int tid = threadIdx.x;           // 256 = 4 waves
  int lane = tid & 63;
  int wave = tid >> 6;
  __shared__ float spi[PD_];
  __shared__ float red[4][PD_];
  if (tid < PD_) spi[tid] = proj[row * PD_ + tid];
  __syncthreads();
  float wv = lnw[lane], bv = lnb[lane];
  float acc = 0.0f;
  for (int j = wave; j < N_; j += 4) {
    int r = j - i; r = r < -64 ? -64 : (r > 64 ? 64 : r); r += 64;
    float v = spi[lane] + proj[(size_t)(b * N_ + j) * PD_ + lane] + relpos[r * PD_ + lane];
    float s = v, s2 = v * v;
    #pragma unroll
    for (int off = 32; off >= 1; off >>= 1) {
      s  += __shfl_xor(s, off, 64);
      s2 += __shfl_xor(s2, off, 64);
    }
    float mean = s * (1.0f / PD_);
    float var = s2 * (1.0f / PD_) - mean * mean;
    acc += (v - mean) * rsqrtf(var + 1e-5f) * wv + bv;
  }
  red[wave][lane] = acc; __syncthreads();
  if (wave == 0) {
    float s = red[0][lane] + red[1][lane] + red[2][lane] + red[3][lane];
    pairm[row * PD_ + lane] = s * (1.0f / N_);
  }
}

// ---------------- head: feat -> silu(fc1) -> fc2 -> rot6d -> frames ----------------
__global__ void head_kernel(const float* __restrict__ x, const float* __restrict__ pairm,
                            const float* __restrict__ Wf1, const float* __restrict__ bWf1,
                            const float* __restrict__ Wf2, const float* __restrict__ bWf2,
                            float* __restrict__ frames) {
  int row = blockIdx.x;
  int tid = threadIdx.x;           // 128
  __shared__ float sfeat[320];
  __shared__ float sg[128];
  __shared__ float sraw[9];
  for (int c = tid; c < 320; c += 128)
    sfeat[c] = (c < D_) ? x[row * D_ + c] : pairm[row * PD_ + (c - D_)];
  __syncthreads();
  float acc = bWf1[tid];
  for (int kk = 0; kk < 320; kk++) acc = fmaf(sfeat[kk], Wf1[kk * 128 + tid], acc);
  sg[tid] = acc / (1.0f + expf(-acc));   // silu
  __syncthreads();
  if (tid < 9) {
    float a2 = bWf2[tid];
    for (int kk = 0; kk < 128; kk++) a2 = fmaf(sg[kk], Wf2[kk * 9 + tid], a2);
    sraw[tid] = a2;
  }
  __syncthreads();
  if (tid == 0) {
    float a1x = sraw[0], a1y = sraw[1], a1z = sraw[2];
    float a2x = sraw[3], a2y = sraw[4], a2z = sraw[5];
    float n1 = sqrtf(a1x * a1x + a1y * a1y + a1z * a1z + 1e-8f);
    float b1x = a1x / n1, b1y = a1y / n1, b1z = a1z / n1;
    float dp = b1x * a2x + b1y * a2y + b1z * a2z;
    float px = a2x - dp * b1x, py = a2y - dp * b1y, pz = a2z - dp * b1z;
    float n2 = sqrtf(px * px + py * py + pz * pz + 1e-8f);
    float b2x = px / n2, b2y = py / n2, b2z = pz / n2;
    float b3x = b1y * b2z - b1z * b2y;
    float b3y = b1z * b2x - b1x * b2z;
    float b3z = b1x * b2y - b1y * b2x;
    float* f = frames + row * 16;
    f[0]  = b1x; f[1]  = b1y; f[2]  = b1z; f[3]  = sraw[6];
    f[4]  = b2x; f[5]  = b2y; f[6]  = b2z; f[7]  = sraw[7];
    f[8]  = b3x; f[9]  = b3y; f[10] = b3z; f[11] = sraw[8];
    f[12] = 0.0f; f[13] = 0.0f; f[14] = 0.0f; f[15] = 1.0f;
  }
}

// ---------------- init / output ----------------
__global__ void init_frames_kernel(float* __restrict__ frames) {
  int i = blockIdx.x * 256 + threadIdx.x;
  if (i < B_ * N_ * 16) {
    int p = i & 15;
    frames[i] = (p == 0 || p == 5 || p == 10 || p == 15) ? 1.0f : 0.0f;
  }
}

__global__ void write_out_kernel(const float* __restrict__ frames, const float* __restrict__ x,
                                 float* __restrict__ out) {
  int i = blockIdx.x * 256 + threadIdx.x;
  const int nf = B_ * N_ * 16;
  const int total = nf + B_ * N_ * D_;
  if (i < nf) out[i] = frames[i];
  else if (i < total) out[i] = x[i - nf];
}

extern "C" void kernel_launch(void* const* d_in, const int* in_sizes, int n_in,
                              void* d_out, int out_size, void* d_ws, size_t ws_size,
                              hipStream_t stream) {
  const int*   tokens    = (const int*)  d_in[0];
  const float* tok_emb   = (const float*)d_in[1];
  const float* emb_ln_w  = (const float*)d_in[2];
  const float* emb_ln_b  = (const float*)d_in[3];
  const float* Wq        = (const float*)d_in[4];
  const float* Wk        = (const float*)d_in[5];
  const float* Wv        = (const float*)d_in[6];
  const float* Wo        = (const float*)d_in[7];
  const float* bo        = (const float*)d_in[8];
  const float* attn_ln_w = (const float*)d_in[9];
  const float* attn_ln_b = (const float*)d_in[10];
  const float* ff_ln_w   = (const float*)d_in[11];
  const float* ff_ln_b   = (const float*)d_in[12];
  const float* W1        = (const float*)d_in[13];
  const float* b1        = (const float*)d_in[14];
  const float* W2        = (const float*)d_in[15];
  const float* b2        = (const float*)d_in[16];
  const float* Wop       = (const float*)d_in[17];
  const float* bop       = (const float*)d_in[18];
  const float* relpos    = (const float*)d_in[19];
  const float* pair_ln_w = (const float*)d_in[20];
  const float* pair_ln_b = (const float*)d_in[21];
  const float* Wf1       = (const float*)d_in[22];
  const float* bWf1      = (const float*)d_in[23];
  const float* Wf2       = (const float*)d_in[24];
  const float* bWf2      = (const float*)d_in[25];

  const int M = B_ * N_;           // 768
  const int XE = M * D_;           // 196608
  // workspace: 110592 + 5*196608 = 1,093,632 floats = 4.37 MB
  float* ws     = (float*)d_ws;
  float* frames = ws;                      // 12288
  float* proj   = frames + M * 16;         // 49152
  float* pairm  = proj   + M * PD_;        // 49152
  float* x      = pairm  + M * PD_;        // XE
  float* q      = x  + XE;                 // XE (also tmp for Wo out)
  float* k      = q  + XE;                 // XE
  float* v      = k  + XE;                 // XE
  float* ao     = v  + XE;                 // XE

  embed_ln_kernel<<<M, 256, 0, stream>>>(tokens, tok_emb, emb_ln_w, emb_ln_b, x);
  init_frames_kernel<<<(B_ * N_ * 16 + 255) / 256, 256, 0, stream>>>(frames);

  for (int l = 0; l < L_; l++) {
    const float* Wql = Wq + (size_t)l * D_ * D_;
    const float* Wkl = Wk + (size_t)l * D_ * D_;
    const float* Wvl = Wv + (size_t)l * D_ * D_;
    const float* Wol = Wo + (size_t)l * D_ * D_;
    gemm_rows_kernel<<<M, 256, 0, stream>>>(x, Wql, nullptr, q, D_, D_, 0);
    gemm_rows_kernel<<<M, 256, 0, stream>>>(x, Wkl, nullptr, k, D_, D_, 0);
    gemm_rows_kernel<<<M, 256, 0, stream>>>(x, Wvl, nullptr, v, D_, D_, 0);
    attn_kernel<<<M * H_, 256, 0, stream>>>(q, k, v, frames, ao);
    // q is dead now; reuse as tmp for Wo output
    gemm_rows_kernel<<<M, 256, 0, stream>>>(ao, Wol, bo + l * D_, q, D_, D_, 0);
    add_ln_kernel<<<M, 256, 0, stream>>>(x, q, attn_ln_w + l * D_, attn_ln_b + l * D_, x);
    fused_ff_kernel<<<M, 256, 0, stream>>>(x, ff_ln_w + l * D_, ff_ln_b + l * D_,
                                           W1 + (size_t)l * D_ * 1024, b1 + l * 1024,
                                           W2 + (size_t)l * 1024 * D_, b2 + l * D_);
    gemm_rows_kernel<<<M, 256, 0, stream>>>(x, Wop, bop, proj, D_, PD_, 1);
    pair_mean_kernel<<<M, 256, 0, stream>>>(proj, relpos, pair_ln_w, pair_ln_b, pairm);
    head_kernel<<<M, 128, 0, stream>>>(x, pairm, Wf1, bWf1, Wf2, bWf2, frames);
  }

  const int total = B_ * N_ * 16 + B_ * N_ * D_;
  write_out_kernel<<<(total + 255) / 256, 256, 0, stream>>>(frames, x, (float*)d_out);
}

// Round 5
// 1874.249 us; speedup vs baseline: 1.3514x; 1.3514x over previous
//
#include <hip/hip_runtime.h>
#include <hip/hip_bf16.h>
#include <math.h>

#define B_  2
#define N_  384
#define D_  256
#define PD_ 64
#define L_  8
#define H_  8
#define DH_ 32

// ---------------- embed + pos-enc + LN ----------------
__global__ void embed_ln_kernel(const int* __restrict__ tokens, const float* __restrict__ tok_emb,
                                const float* __restrict__ lnw, const float* __restrict__ lnb,
                                float* __restrict__ x) {
  int row = blockIdx.x;            // b*N + n
  int n = row % N_;
  int d = threadIdx.x;             // 0..255
  int tok = tokens[row];
  float val = tok_emb[tok * D_ + d];
  int i = d >> 1;
  float dv = expf((float)(2 * i) * (-logf(10000.0f) / (float)D_));
  float ang = (float)n * dv;
  val += (d & 1) ? cosf(ang) : sinf(ang);

  __shared__ float rbuf[256];
  rbuf[d] = val; __syncthreads();
  for (int s = 128; s > 0; s >>= 1) { if (d < s) rbuf[d] += rbuf[d + s]; __syncthreads(); }
  float mean = rbuf[0] / D_;
  __syncthreads();
  rbuf[d] = val * val; __syncthreads();
  for (int s = 128; s > 0; s >>= 1) { if (d < s) rbuf[d] += rbuf[d + s]; __syncthreads(); }
  float var = rbuf[0] / D_ - mean * mean;
  float r = rsqrtf(var + 1e-5f);
  x[row * D_ + d] = (val - mean) * r * lnw[d] + lnb[d];
}

// ---------------- fused QKV: 3 matmuls sharing the LDS row ----------------
__global__ void qkv_kernel(const float* __restrict__ x, const float* __restrict__ Wq,
                           const float* __restrict__ Wk, const float* __restrict__ Wv,
                           float* __restrict__ q, float* __restrict__ k, float* __restrict__ v) {
  int row = blockIdx.x;
  int c = threadIdx.x;             // 256
  __shared__ __align__(16) float sA[D_];
  if (c < 64) ((float4*)sA)[c] = ((const float4*)(x + row * D_))[c];
  __syncthreads();
  float aq = 0.f, ak = 0.f, av = 0.f;
  for (int kk = 0; kk < D_; kk++) {
    float a = sA[kk];
    aq = fmaf(a, Wq[(size_t)kk * D_ + c], aq);
    ak = fmaf(a, Wk[(size_t)kk * D_ + c], ak);
    av = fmaf(a, Wv[(size_t)kk * D_ + c], av);
  }
  q[row * D_ + c] = aq; k[row * D_ + c] = ak; v[row * D_ + c] = av;
}

// ---------------- generic per-row GEMM (Wo): C = A@W + bias ----------------
__global__ void gemm_rows_kernel(const float* __restrict__ A, const float* __restrict__ W,
                                 const float* __restrict__ bias, float* __restrict__ C,
                                 int K, int Nc) {
  int row = blockIdx.x;
  int tid = threadIdx.x;
  __shared__ __align__(16) float sA[256];
  if (tid < 64) ((float4*)sA)[tid] = ((const float4*)(A + row * K))[tid];
  __syncthreads();
  for (int c = tid; c < Nc; c += 256) {
    float a0 = 0.f, a1 = 0.f, a2 = 0.f, a3 = 0.f;
    const float* wp = W + c;
    for (int kk = 0; kk < K; kk += 4) {
      a0 = fmaf(sA[kk],     wp[(size_t)kk * Nc],           a0);
      a1 = fmaf(sA[kk + 1], wp[(size_t)(kk + 1) * Nc],     a1);
      a2 = fmaf(sA[kk + 2], wp[(size_t)(kk + 2) * Nc],     a2);
      a3 = fmaf(sA[kk + 3], wp[(size_t)(kk + 3) * Nc],     a3);
    }
    C[row * Nc + c] = (bias ? bias[c] : 0.f) + (a0 + a1) + (a2 + a3);
  }
}

// ---------------- SE3 frame attention: one block per (b,i,h) ----------------
__global__ void attn_kernel(const float* __restrict__ Q, const float* __restrict__ K,
                            const float* __restrict__ V, const float* __restrict__ frames,
                            float* __restrict__ AO) {
  int idx = blockIdx.x;
  int h = idx % H_;
  int bi = idx / H_;               // b*N + i
  int b = bi / N_;
  int tid = threadIdx.x;           // 256
  __shared__ __align__(16) float sq[DH_];
  __shared__ float sc[N_];
  __shared__ float rbuf[256];
  if (tid < DH_) sq[tid] = Q[bi * D_ + h * DH_ + tid];
  float ti0 = frames[bi * 16 + 3], ti1 = frames[bi * 16 + 7], ti2 = frames[bi * 16 + 11];
  __syncthreads();
  const float4* sq4 = (const float4*)sq;
  for (int j = tid; j < N_; j += 256) {
    int bj = b * N_ + j;
    const float4* kp4 = (const float4*)(K + (size_t)bj * D_ + h * DH_);
    float d0 = 0.f, d1 = 0.f, d2 = 0.f, d3 = 0.f;
    #pragma unroll
    for (int q8 = 0; q8 < 8; q8++) {
      float4 kv = kp4[q8], qv = sq4[q8];
      d0 = fmaf(qv.x, kv.x, d0); d1 = fmaf(qv.y, kv.y, d1);
      d2 = fmaf(qv.z, kv.z, d2); d3 = fmaf(qv.w, kv.w, d3);
    }
    float dot = (d0 + d1) + (d2 + d3);
    float dx = ti0 - frames[bj * 16 + 3];
    float dy = ti1 - frames[bj * 16 + 7];
    float dz = ti2 - frames[bj * 16 + 11];
    sc[j] = dot * 0.17677669529663689f - (dx * dx + dy * dy + dz * dz);
  }
  __syncthreads();
  float m = -1e30f;
  for (int j = tid; j < N_; j += 256) m = fmaxf(m, sc[j]);
  rbuf[tid] = m; __syncthreads();
  for (int s = 128; s > 0; s >>= 1) { if (tid < s) rbuf[tid] = fmaxf(rbuf[tid], rbuf[tid + s]); __syncthreads(); }
  m = rbuf[0]; __syncthreads();
  float ps = 0.0f;
  for (int j = tid; j < N_; j += 256) { float e = expf(sc[j] - m); sc[j] = e; ps += e; }
  rbuf[tid] = ps; __syncthreads();
  for (int s = 128; s > 0; s >>= 1) { if (tid < s) rbuf[tid] += rbuf[tid + s]; __syncthreads(); }
  float inv = 1.0f / rbuf[0];
  __syncthreads();
  int dd = tid & (DH_ - 1);
  int g  = tid >> 5;               // 0..7
  float acc = 0.0f;
  for (int j = g; j < N_; j += 8)
    acc = fmaf(sc[j], V[(size_t)(b * N_ + j) * D_ + h * DH_ + dd], acc);
  rbuf[tid] = acc; __syncthreads();
  if (tid < DH_) {
    float s = 0.0f;
    #pragma unroll
    for (int gg = 0; gg < 8; gg++) s += rbuf[gg * 32 + tid];
    AO[bi * D_ + h * DH_ + tid] = s * inv;
  }
}

// ---------------- x = LN(x + add) ----------------
__global__ void add_ln_kernel(const float* __restrict__ X, const float* __restrict__ Add,
                              const float* __restrict__ lnw, const float* __restrict__ lnb,
                              float* __restrict__ Out) {
  int row = blockIdx.x;
  int d = threadIdx.x;
  float val = X[row * D_ + d] + Add[row * D_ + d];
  __shared__ float rbuf[256];
  rbuf[d] = val; __syncthreads();
  for (int s = 128; s > 0; s >>= 1) { if (d < s) rbuf[d] += rbuf[d + s]; __syncthreads(); }
  float mean = rbuf[0] / D_;
  __syncthreads();
  rbuf[d] = val * val; __syncthreads();
  for (int s = 128; s > 0; s >>= 1) { if (d < s) rbuf[d] += rbuf[d + s]; __syncthreads(); }
  float var = rbuf[0] / D_ - mean * mean;
  float r = rsqrtf(var + 1e-5f);
  Out[row * D_ + d] = (val - mean) * r * lnw[d] + lnb[d];
}

// ---------------- fused FF: x += gelu(LN(x)@W1+b1)@W2+b2 ----------------
__global__ void fused_ff_kernel(float* __restrict__ x,
                                const float* __restrict__ lnw, const float* __restrict__ lnb,
                                const float* __restrict__ W1, const float* __restrict__ b1,
                                const float* __restrict__ W2, const float* __restrict__ b2) {
  int row = blockIdx.x;
  int tid = threadIdx.x;           // 256
  __shared__ float sh[256];
  __shared__ float sf[1024];
  __shared__ float rbuf[256];
  float xv = x[row * D_ + tid];
  rbuf[tid] = xv; __syncthreads();
  for (int s = 128; s > 0; s >>= 1) { if (tid < s) rbuf[tid] += rbuf[tid + s]; __syncthreads(); }
  float mean = rbuf[0] / D_;
  __syncthreads();
  rbuf[tid] = xv * xv; __syncthreads();
  for (int s = 128; s > 0; s >>= 1) { if (tid < s) rbuf[tid] += rbuf[tid + s]; __syncthreads(); }
  float var = rbuf[0] / D_ - mean * mean;
  float r = rsqrtf(var + 1e-5f);
  sh[tid] = (xv - mean) * r * lnw[tid] + lnb[tid];
  __syncthreads();
  for (int c = tid; c < 1024; c += 256) {
    float a0 = 0.f, a1 = 0.f, a2 = 0.f, a3 = 0.f;
    const float* wp = W1 + c;
    for (int kk = 0; kk < 256; kk += 4) {
      a0 = fmaf(sh[kk],     wp[(size_t)kk * 1024],       a0);
      a1 = fmaf(sh[kk + 1], wp[(size_t)(kk + 1) * 1024], a1);
      a2 = fmaf(sh[kk + 2], wp[(size_t)(kk + 2) * 1024], a2);
      a3 = fmaf(sh[kk + 3], wp[(size_t)(kk + 3) * 1024], a3);
    }
    float acc = b1[c] + (a0 + a1) + (a2 + a3);
    sf[c] = 0.5f * acc * (1.0f + erff(acc * 0.7071067811865475f));
  }
  __syncthreads();
  float a0 = 0.f, a1 = 0.f, a2 = 0.f, a3 = 0.f;
  const float* wp2 = W2 + tid;
  for (int kk = 0; kk < 1024; kk += 4) {
    a0 = fmaf(sf[kk],     wp2[(size_t)kk * 256],       a0);
    a1 = fmaf(sf[kk + 1], wp2[(size_t)(kk + 1) * 256], a1);
    a2 = fmaf(sf[kk + 2], wp2[(size_t)(kk + 2) * 256], a2);
    a3 = fmaf(sf[kk + 3], wp2[(size_t)(kk + 3) * 256], a3);
  }
  x[row * D_ + tid] = xv + b2[tid] + (a0 + a1) + (a2 + a3);
}

// ---------------- proj = relu(x@Wop+bop), plus row mean ----------------
__global__ void proj_mean_kernel(const float* __restrict__ x, const float* __restrict__ Wop,
                                 const float* __restrict__ bop,
                                 float* __restrict__ proj, float* __restrict__ mp) {
  int row = blockIdx.x;
  int c = threadIdx.x;             // 64 (one wave)
  __shared__ __align__(16) float sA[D_];
  ((float4*)sA)[c] = ((const float4*)(x + row * D_))[c];
  __syncthreads();
  float a0 = 0.f, a1 = 0.f, a2 = 0.f, a3 = 0.f;
  for (int kk = 0; kk < D_; kk += 4) {
    a0 = fmaf(sA[kk],     Wop[(kk)     * PD_ + c], a0);
    a1 = fmaf(sA[kk + 1], Wop[(kk + 1) * PD_ + c], a1);
    a2 = fmaf(sA[kk + 2], Wop[(kk + 2) * PD_ + c], a2);
    a3 = fmaf(sA[kk + 3], Wop[(kk + 3) * PD_ + c], a3);
  }
  float acc = fmaxf(bop[c] + (a0 + a1) + (a2 + a3), 0.0f);
  proj[row * PD_ + c] = acc;
  float s = acc;
  #pragma unroll
  for (int off = 32; off >= 1; off >>= 1) s += __shfl_xor(s, off, 64);
  if (c == 0) mp[row] = s * (1.0f / PD_);
}

// ---------------- rel row means (once per launch) ----------------
__global__ void rel_mean_kernel(const float* __restrict__ relpos, float* __restrict__ mr) {
  int r = blockIdx.x;              // 129
  int c = threadIdx.x;             // 64
  float s = relpos[r * PD_ + c];
  #pragma unroll
  for (int off = 32; off >= 1; off >>= 1) s += __shfl_xor(s, off, 64);
  if (c == 0) mr[r] = s * (1.0f / PD_);
}

// ---------------- pairm init: pairm[row][c] = lnb[c] ----------------
__global__ void init_pairm_kernel(const float* __restrict__ lnb, float* __restrict__ pairm) {
  int idx = blockIdx.x * 256 + threadIdx.x;
  if (idx < B_ * N_ * PD_) pairm[idx] = lnb[idx & (PD_ - 1)];
}

// ---------------- pair LN + mean over j (analytic mean, 1 shuffle chain) ----------------
// grid = M*2 (2 j-half blocks per row); accumulates w*sum(d*rinv)/N into pairm via atomics
__global__ void pair_mean_kernel(const float* __restrict__ proj, const float* __restrict__ relpos,
                                 const float* __restrict__ mp, const float* __restrict__ mr,
                                 const float* __restrict__ lnw, float* __restrict__ pairm) {
  int row  = blockIdx.x >> 1;      // b*N + i
  int half = blockIdx.x & 1;
  int b = row / N_;
  int i = row % N_;
  int tid = threadIdx.x;           // 256 = 4 waves
  int lane = tid & 63;
  int wave = tid >> 6;
  __shared__ float red[4][PD_];
  float vpi = proj[row * PD_ + lane];
  float mpi = mp[row];
  const float* pb  = proj + (size_t)b * N_ * PD_;
  const float* mpb = mp + b * N_;
  float acc = 0.0f;
  int jend = (half + 1) * (N_ / 2);
  for (int j = half * (N_ / 2) + wave * 2; j < jend; j += 8) {
    int ja = j, jb = j + 1;
    int ra = ja - i; ra = ra < -64 ? -64 : (ra > 64 ? 64 : ra); ra += 64;
    int rb = jb - i; rb = rb < -64 ? -64 : (rb > 64 ? 64 : rb); rb += 64;
    float va = vpi + pb[ja * PD_ + lane] + relpos[ra * PD_ + lane];
    float vb = vpi + pb[jb * PD_ + lane] + relpos[rb * PD_ + lane];
    float da = va - (mpi + mpb[ja] + mr[ra]);
    float db = vb - (mpi + mpb[jb] + mr[rb]);
    float s2a = da * da, s2b = db * db;
    #pragma unroll
    for (int off = 32; off >= 1; off >>= 1) {
      s2a += __shfl_xor(s2a, off, 64);
      s2b += __shfl_xor(s2b, off, 64);
    }
    float rinva = rsqrtf(s2a * (1.0f / PD_) + 1e-5f);
    float rinvb = rsqrtf(s2b * (1.0f / PD_) + 1e-5f);
    acc += da * rinva + db * rinvb;
  }
  red[wave][lane] = acc; __syncthreads();
  if (wave == 0) {
    float s = red[0][lane] + red[1][lane] + red[2][lane] + red[3][lane];
    atomicAdd(&pairm[row * PD_ + lane], s * lnw[lane] * (1.0f / N_));
  }
}

// ---------------- head: feat -> silu(fc1) -> fc2 -> rot6d -> frames ----------------
__global__ void head_kernel(const float* __restrict__ x, const float* __restrict__ pairm,
                            const float* __restrict__ Wf1, const float* __restrict__ bWf1,
                            const float* __restrict__ Wf2, const float* __restrict__ bWf2,
                            float* __restrict__ frames) {
  int row = blockIdx.x;
  int tid = threadIdx.x;           // 128
  __shared__ float sfeat[320];
  __shared__ float sg[128];
  __shared__ float sraw[9];
  for (int c = tid; c < 320; c += 128)
    sfeat[c] = (c < D_) ? x[row * D_ + c] : pairm[row * PD_ + (c - D_)];
  __syncthreads();
  float a0 = 0.f, a1 = 0.f, a2 = 0.f, a3 = 0.f;
  for (int kk = 0; kk < 320; kk += 4) {
    a0 = fmaf(sfeat[kk],     Wf1[(kk)     * 128 + tid], a0);
    a1 = fmaf(sfeat[kk + 1], Wf1[(kk + 1) * 128 + tid], a1);
    a2 = fmaf(sfeat[kk + 2], Wf1[(kk + 2) * 128 + tid], a2);
    a3 = fmaf(sfeat[kk + 3], Wf1[(kk + 3) * 128 + tid], a3);
  }
  float acc = bWf1[tid] + (a0 + a1) + (a2 + a3);
  sg[tid] = acc / (1.0f + expf(-acc));   // silu
  __syncthreads();
  if (tid < 9) {
    float b0 = 0.f, b1v = 0.f;
    for (int kk = 0; kk < 128; kk += 2) {
      b0  = fmaf(sg[kk],     Wf2[(kk)     * 9 + tid], b0);
      b1v = fmaf(sg[kk + 1], Wf2[(kk + 1) * 9 + tid], b1v);
    }
    sraw[tid] = bWf2[tid] + b0 + b1v;
  }
  __syncthreads();
  if (tid == 0) {
    float a1x = sraw[0], a1y = sraw[1], a1z = sraw[2];
    float a2x = sraw[3], a2y = sraw[4], a2z = sraw[5];
    float n1 = sqrtf(a1x * a1x + a1y * a1y + a1z * a1z + 1e-8f);
    float b1x = a1x / n1, b1y = a1y / n1, b1z = a1z / n1;
    float dp = b1x * a2x + b1y * a2y + b1z * a2z;
    float px = a2x - dp * b1x, py = a2y - dp * b1y, pz = a2z - dp * b1z;
    float n2 = sqrtf(px * px + py * py + pz * pz + 1e-8f);
    float b2x = px / n2, b2y = py / n2, b2z = pz / n2;
    float b3x = b1y * b2z - b1z * b2y;
    float b3y = b1z * b2x - b1x * b2z;
    float b3z = b1x * b2y - b1y * b2x;
    float* f = frames + row * 16;
    f[0]  = b1x; f[1]  = b1y; f[2]  = b1z; f[3]  = sraw[6];
    f[4]  = b2x; f[5]  = b2y; f[6]  = b2z; f[7]  = sraw[7];
    f[8]  = b3x; f[9]  = b3y; f[10] = b3z; f[11] = sraw[8];
    f[12] = 0.0f; f[13] = 0.0f; f[14] = 0.0f; f[15] = 1.0f;
  }
}

// ---------------- init / output ----------------
__global__ void init_frames_kernel(float* __restrict__ frames) {
  int i = blockIdx.x * 256 + threadIdx.x;
  if (i < B_ * N_ * 16) {
    int p = i & 15;
    frames[i] = (p == 0 || p == 5 || p == 10 || p == 15) ? 1.0f : 0.0f;
  }
}

__global__ void write_out_kernel(const float* __restrict__ frames, const float* __restrict__ x,
                                 float* __restrict__ out) {
  int i = blockIdx.x * 256 + threadIdx.x;
  const int nf = B_ * N_ * 16;
  const int total = nf + B_ * N_ * D_;
  if (i < nf) out[i] = frames[i];
  else if (i < total) out[i] = x[i - nf];
}

extern "C" void kernel_launch(void* const* d_in, const int* in_sizes, int n_in,
                              void* d_out, int out_size, void* d_ws, size_t ws_size,
                              hipStream_t stream) {
  const int*   tokens    = (const int*)  d_in[0];
  const float* tok_emb   = (const float*)d_in[1];
  const float* emb_ln_w  = (const float*)d_in[2];
  const float* emb_ln_b  = (const float*)d_in[3];
  const float* Wq        = (const float*)d_in[4];
  const float* Wk        = (const float*)d_in[5];
  const float* Wv        = (const float*)d_in[6];
  const float* Wo        = (const float*)d_in[7];
  const float* bo        = (const float*)d_in[8];
  const float* attn_ln_w = (const float*)d_in[9];
  const float* attn_ln_b = (const float*)d_in[10];
  const float* ff_ln_w   = (const float*)d_in[11];
  const float* ff_ln_b   = (const float*)d_in[12];
  const float* W1        = (const float*)d_in[13];
  const float* b1        = (const float*)d_in[14];
  const float* W2        = (const float*)d_in[15];
  const float* b2        = (const float*)d_in[16];
  const float* Wop       = (const float*)d_in[17];
  const float* bop       = (const float*)d_in[18];
  const float* relpos    = (const float*)d_in[19];
  const float* pair_ln_w = (const float*)d_in[20];
  const float* pair_ln_b = (const float*)d_in[21];
  const float* Wf1       = (const float*)d_in[22];
  const float* bWf1      = (const float*)d_in[23];
  const float* Wf2       = (const float*)d_in[24];
  const float* bWf2      = (const float*)d_in[25];

  const int M = B_ * N_;           // 768
  const int XE = M * D_;           // 196608
  float* ws     = (float*)d_ws;
  float* frames = ws;                      // 12288
  float* proj   = frames + M * 16;         // 49152
  float* pairm  = proj   + M * PD_;        // 49152
  float* mp     = pairm  + M * PD_;        // 768
  float* mr     = mp     + M;              // 129 (pad to 192)
  float* x      = mr     + 192;            // XE
  float* q      = x  + XE;                 // XE (also tmp for Wo out)
  float* k      = q  + XE;                 // XE
  float* v      = k  + XE;                 // XE
  float* ao     = v  + XE;                 // XE
  // total ≈ 1.094M floats ≈ 4.38 MB

  embed_ln_kernel<<<M, 256, 0, stream>>>(tokens, tok_emb, emb_ln_w, emb_ln_b, x);
  init_frames_kernel<<<(B_ * N_ * 16 + 255) / 256, 256, 0, stream>>>(frames);
  rel_mean_kernel<<<129, 64, 0, stream>>>(relpos, mr);

  for (int l = 0; l < L_; l++) {
    qkv_kernel<<<M, 256, 0, stream>>>(x, Wq + (size_t)l * D_ * D_, Wk + (size_t)l * D_ * D_,
                                      Wv + (size_t)l * D_ * D_, q, k, v);
    attn_kernel<<<M * H_, 256, 0, stream>>>(q, k, v, frames, ao);
    // q is dead now; reuse as tmp for Wo output
    gemm_rows_kernel<<<M, 256, 0, stream>>>(ao, Wo + (size_t)l * D_ * D_, bo + l * D_, q, D_, D_);
    add_ln_kernel<<<M, 256, 0, stream>>>(x, q, attn_ln_w + l * D_, attn_ln_b + l * D_, x);
    fused_ff_kernel<<<M, 256, 0, stream>>>(x, ff_ln_w + l * D_, ff_ln_b + l * D_,
                                           W1 + (size_t)l * D_ * 1024, b1 + l * 1024,
                                           W2 + (size_t)l * 1024 * D_, b2 + l * D_);
    proj_mean_kernel<<<M, 64, 0, stream>>>(x, Wop, bop, proj, mp);
    init_pairm_kernel<<<(M * PD_ + 255) / 256, 256, 0, stream>>>(pair_ln_b, pairm);
    pair_mean_kernel<<<M * 2, 256, 0, stream>>>(proj, relpos, mp, mr, pair_ln_w, pairm);
    head_kernel<<<M, 128, 0, stream>>>(x, pairm, Wf1, bWf1, Wf2, bWf2, frames);
  }

  const int total = B_ * N_ * 16 + B_ * N_ * D_;
  write_out_kernel<<<(total + 255) / 256, 256, 0, stream>>>(frames, x, (float*)d_out);
}